// Round 21
// baseline (80.268 us; speedup 1.0000x reference)
//
#include <hip/hip_runtime.h>
#include <math.h>

#define B_  4
#define C1_ 256
#define C2_ 256
#define H_  64
#define W_  64
#define HW_ 4096
#define KK_ 9

// ws byte offsets (total ~30 MB; ws >= 97 MB proven in R9)
#define A_WA     0u           // bf16 Wa[72][4][256][8]       1,179,648
#define A_XT     1179648u     // bf16 xT[B][HW][C1]           8,388,608  (pos-major)
#define A_XPAIR  9568256u     // uint xpair[B][HW][C1]       16,777,216  (pos-major pairs)
#define A_MIDX   26345472u    // int2 midx[B][9][4096]        1,179,648
#define A_MWGT   27525120u    // float4 mwgt[B][9][4096]      2,359,296
#define A_WOM    29884416u    // bf16 Wom[72][4][32][8]         147,456
#define A_BN     30031872u    // float inv[256]; bb[256]          2,048

typedef short bf16x8 __attribute__((ext_vector_type(8)));
typedef float f32x4 __attribute__((ext_vector_type(4)));

__device__ __forceinline__ unsigned f2bfu(float f) {
  unsigned u = __builtin_bit_cast(unsigned, f);
  return (u + 0x7FFFu + ((u >> 16) & 1u)) >> 16;
}
__device__ __forceinline__ float bflo(unsigned g) {
  return __builtin_bit_cast(float, g << 16);
}
__device__ __forceinline__ float bfhi(unsigned g) {
  return __builtin_bit_cast(float, g & 0xFFFF0000u);
}
__device__ __forceinline__ void gload_lds16(const void* g, void* l) {
  __builtin_amdgcn_global_load_lds(
      (const __attribute__((address_space(1))) unsigned*)g,
      (__attribute__((address_space(3))) unsigned*)l, 16, 0, 0);
}

// grid 512: 8 XCDs; each XCD owns 32 consecutive rows of ONE batch.
__device__ __forceinline__ void decode_bid512(int bid, int& b, int& h, int& ph) {
  const int xcd = bid & 7, slot = bid >> 3;
  b = xcd >> 1;
  h = (xcd & 1) * 32 + (slot >> 1);
  ph = slot & 1;
}

// grid 256 variant: one full row h per block.
__device__ __forceinline__ void decode_bid256(int bid, int& b, int& h) {
  const int xcd = bid & 7, slot = bid >> 3;
  b = xcd >> 1;
  h = (xcd & 1) * 32 + slot;
}

// ---------------------------------------------------------------------------
// prep: transpose producing BOTH xT (bf16) and xpair (packed pos-pairs)
// (blocks 0..1023) + wt_perm (1024..3327) + wom_perm/BN (3328..3615).
// ---------------------------------------------------------------------------
__global__ __launch_bounds__(256) void prep(
    const float* __restrict__ x, const float* __restrict__ w_om,
    const float* __restrict__ w_dcn, const float* __restrict__ bn_gamma,
    const float* __restrict__ bn_beta, const float* __restrict__ bn_mean,
    const float* __restrict__ bn_var, unsigned short* __restrict__ xT,
    unsigned* __restrict__ xpair, unsigned short* __restrict__ Wa,
    unsigned short* __restrict__ Wom, float* __restrict__ bnbuf) {
  const int bid = blockIdx.x;
  const int tid = threadIdx.x;
  if (bid < 1024) {
    __shared__ unsigned short T[64][68];  // [c][pos-local 0..64], padded
    const int b = bid >> 8;
    const int rem = bid & 255;
    const int pos0 = (rem >> 2) * 64;
    const int c0 = (rem & 3) * 64;
    const int pl = tid & 63;
    const int ch = tid >> 6;
#pragma unroll
    for (int r = 0; r < 16; ++r) {
      const int cl = ch * 16 + r;
      const float v = x[((size_t)(b * C1_ + c0 + cl)) * HW_ + pos0 + pl];
      T[cl][pl] = (unsigned short)f2bfu(v);
    }
    if (tid < 64) {
      const int pe = min(pos0 + 64, HW_ - 1);
      T[tid][64] =
          (unsigned short)f2bfu(x[((size_t)(b * C1_ + c0 + tid)) * HW_ + pe]);
    }
    __syncthreads();
    unsigned short* dstT = xT + ((size_t)b * HW_ + pos0) * 256 + c0;
#pragma unroll
    for (int it = 0; it < 2; ++it) {
      const int q = it * 256 + tid;
      const int pp = q >> 3, cc = (q & 7) * 8;
      unsigned t0 = T[cc + 0][pp], t1 = T[cc + 1][pp], t2 = T[cc + 2][pp],
               t3 = T[cc + 3][pp], t4 = T[cc + 4][pp], t5 = T[cc + 5][pp],
               t6 = T[cc + 6][pp], t7 = T[cc + 7][pp];
      *(int4*)(dstT + (size_t)pp * 256 + cc) =
          make_int4(t0 | (t1 << 16), t2 | (t3 << 16), t4 | (t5 << 16),
                    t6 | (t7 << 16));
    }
    unsigned* dstP = xpair + ((size_t)b * HW_ + pos0) * 256 + c0;
#pragma unroll
    for (int it = 0; it < 4; ++it) {
      const int q = it * 256 + tid;
      const int pp = q >> 4;
      const int cc = (q & 15) * 4;
      unsigned p0 = (unsigned)T[cc + 0][pp] | ((unsigned)T[cc + 0][pp + 1] << 16);
      unsigned p1 = (unsigned)T[cc + 1][pp] | ((unsigned)T[cc + 1][pp + 1] << 16);
      unsigned p2 = (unsigned)T[cc + 2][pp] | ((unsigned)T[cc + 2][pp + 1] << 16);
      unsigned p3 = (unsigned)T[cc + 3][pp] | ((unsigned)T[cc + 3][pp + 1] << 16);
      *(uint4*)(dstP + (size_t)pp * 256 + cc) = make_uint4(p0, p1, p2, p3);
    }
  } else if (bid < 1024 + 2304) {
    const unsigned e = (bid - 1024) * 256 + tid;  // < 589824
    const unsigned kt = e >> 13, r2 = e & 8191;
    const unsigned kg = r2 >> 11, r3 = r2 & 2047, o = r3 >> 3, j = r3 & 7;
    const unsigned ck = kt * 32 + kg * 8 + j;
    const unsigned k = ck >> 8, c = ck & 255;
    Wa[e] = (unsigned short)f2bfu(w_dcn[((size_t)o * C1_ + c) * 9 + k]);
  } else {
    const int wb = bid - (1024 + 2304);
    if (wb == 0) {
      const int o = tid;
      float inv = bn_gamma[o] * rsqrtf(bn_var[o] + 1e-5f);
      bnbuf[o] = inv;
      bnbuf[256 + o] = bn_beta[o] - bn_mean[o] * inv;
    }
    const unsigned e = wb * 256 + tid;  // < 73728
    const unsigned kt = e >> 10, kg = (e >> 8) & 3, o = (e >> 3) & 31, j = e & 7;
    const unsigned ck = kt * 32 + kg * 8 + j;
    const unsigned k = ck >> 8, c = ck & 255;
    const float v = (o < 27) ? w_om[((size_t)o * C1_ + c) * 9 + k] : 0.f;
    Wom[e] = (unsigned short)f2bfu(v);
  }
}

// ---------------------------------------------------------------------------
// om_gemm: unchanged (xT producer). BK=128, 18 steps, grid 512.
// ---------------------------------------------------------------------------
__global__ __launch_bounds__(256) void om_gemm(
    const unsigned short* __restrict__ xT, const float* __restrict__ b_om,
    const unsigned short* __restrict__ Wom, int2* __restrict__ midx,
    float4* __restrict__ mwgt) {
  __shared__ short Ald[2][4096];
  __shared__ short Bld[2][4096];
  __shared__ float omld[32][33];

  int b, h, ph;
  decode_bid512(blockIdx.x, b, h, ph);
  const int tid = threadIdx.x;
  const int lane = tid & 63, wid = tid >> 6;
  const int wo = wid >> 1, wp = wid & 1;
  const int p = tid & 31;
  const int cr = tid >> 5;

  const unsigned short* xTb = xT + (size_t)b * HW_ * 256;

  f32x4 acc = (f32x4){0.f, 0.f, 0.f, 0.f};

  auto stageA = [&](int s, int buf) {
    const char* src = (const char*)(Wom + (size_t)s * 4096);
    gload_lds16(src + tid * 16, (char*)&Ald[buf][0] + tid * 16);
    gload_lds16(src + (256 + tid) * 16, (char*)&Ald[buf][0] + (256 + tid) * 16);
  };

  auto produce = [&](int s, int4& uA, int4& uB) {
    const int k = s >> 1;
    const int c0 = (s & 1) * 128 + cr * 16;
    const int hh = h - 1 + k / 3;
    const int ww = ph * 32 + p - 1 + k % 3;
    const bool v = ((unsigned)hh < (unsigned)H_) && ((unsigned)ww < (unsigned)W_);
    const unsigned short* pl = xTb + (size_t)(v ? hh * W_ + ww : 0) * 256 + c0;
    uA = v ? *(const int4*)pl : make_int4(0, 0, 0, 0);
    uB = v ? *(const int4*)(pl + 8) : make_int4(0, 0, 0, 0);
  };

  const int bslot = (cr * 2) * 256 + p * 8;

  auto compute = [&](int buf) {
    const int kg = lane >> 4, rr = lane & 15;
#pragma unroll
    for (int kh = 0; kh < 4; ++kh) {
      bf16x8 af = *(const bf16x8*)&Ald[buf][(kh * 4 + kg) * 256 + (wo * 16 + rr) * 8];
      bf16x8 bfr = *(const bf16x8*)&Bld[buf][(kh * 4 + kg) * 256 + (wp * 16 + rr) * 8];
      acc = __builtin_amdgcn_mfma_f32_16x16x32_bf16(af, bfr, acc, 0, 0, 0);
    }
  };

  {
    int4 uA, uB;
    produce(0, uA, uB);
    *(int4*)&Bld[0][bslot] = uA;
    *(int4*)&Bld[0][bslot + 256] = uB;
    stageA(0, 0);
  }
  __syncthreads();

  for (int s = 0; s < 18; ++s) {
    const int cur = s & 1, nxt = cur ^ 1;
    const bool pre = (s < 17);
    int4 uA, uB;
    if (pre) {
      produce(s + 1, uA, uB);
      stageA(s + 1, nxt);
    }
    compute(cur);
    if (pre) {
      *(int4*)&Bld[nxt][bslot] = uA;
      *(int4*)&Bld[nxt][bslot + 256] = uB;
    }
    __syncthreads();
  }

  {
    const int rr = lane & 15, rh = lane >> 4;
#pragma unroll
    for (int r = 0; r < 4; ++r) omld[wo * 16 + rh * 4 + r][wp * 16 + rr] = acc[r];
  }
  __syncthreads();

  if (tid < 32) {
    const int pc = tid;
    float a[27];
#pragma unroll
    for (int oc = 0; oc < 27; ++oc) a[oc] = omld[oc][pc] + b_om[oc];

    const int pcol = ph * 32 + pc;
#pragma unroll
    for (int k = 0; k < 9; ++k) {
      float dy = fminf(fmaxf(a[2 * k], -6.f), 6.f);
      float dx = fminf(fmaxf(a[2 * k + 1], -6.f), 6.f);
      float m = 1.f / (1.f + expf(-a[18 + k]));
      float py = (float)(h - 1 + k / 3) + dy;
      float px = (float)(pcol - 1 + k % 3) + dx;
      float y0f = floorf(py), x0f = floorf(px);
      float ly = py - y0f, lx = px - x0f;
      int y0 = (int)y0f, x0 = (int)x0f;
      int y1 = y0 + 1, x1 = x0 + 1;
      const bool vy0 = ((unsigned)y0 < (unsigned)H_);
      const bool vy1 = ((unsigned)y1 < (unsigned)H_);
      const bool vx0 = ((unsigned)x0 < (unsigned)W_);
      const bool vx1 = ((unsigned)x1 < (unsigned)W_);
      int y0c = min(max(y0, 0), H_ - 1), y1c = min(max(y1, 0), H_ - 1);
      int x0c = min(max(x0, 0), W_ - 1), x1c = min(max(x1, 0), W_ - 1);
      const int xbc = min(max(x0, 0), W_ - 2);
      float wx0 = 0.f, wx1 = 0.f;
      if (vx0) { if (x0c == xbc) wx0 += 1.f - lx; else wx1 += 1.f - lx; }
      if (vx1) { if (x1c == xbc) wx0 += lx; else wx1 += lx; }
      const float wy0 = vy0 ? (1.f - ly) : 0.f;
      const float wy1 = vy1 ? ly : 0.f;
      const size_t e = ((size_t)b * KK_ + k) * HW_ + h * W_ + pcol;
      midx[e] = make_int2(y0c * W_ + xbc, y1c * W_ + xbc);
      mwgt[e] = make_float4(m * wy0 * wx0, m * wy0 * wx1, m * wy1 * wx0,
                            m * wy1 * wx1);
    }
  }
}

// ---------------------------------------------------------------------------
// dcn_fused: block 256o x 64p, 512 thr = 8 waves (4 wo x 2 wp), wave tile
// 64o x 32p -> 12 operand ds_reads per 16 MFMA (0.75 rd/MFMA, was 1.0);
// block-step LDS reads 96 KB (was 128). BK=64, 36 steps, LDS 80 KB.
// SIMPLE proven __syncthreads pipeline (R16 style): issue -> stageA ->
// compute -> pack -> sync. Correct by construction — no asm vmcnt
// bookkeeping (R20's counted-vmcnt mis-ordered and corrupted Ald).
// Producer: col = tid>>3, q = tid&7 (8 ck each): 4 uint4 gathers (8-lane
// 128B contiguous row segments), 1 int4 B-write at page = q (XOR swizzle).
// ---------------------------------------------------------------------------
__global__ __launch_bounds__(512) void dcn_fused(
    const unsigned short* __restrict__ Wa, const unsigned* __restrict__ xpair,
    const int2* __restrict__ midxg, const float4* __restrict__ mwgtg,
    const float* __restrict__ bnbuf, float* __restrict__ out) {
  __shared__ short Ald[2][16384];  // [2 kh][4 kg][256 o][8 j]  32 KB/buf
  __shared__ short Bld[2][4096];   // [2 kh][4 kg][64 col'][8 j] 8 KB/buf

  int b, h;
  decode_bid256(blockIdx.x, b, h);
  const int tid = threadIdx.x;
  const int lane = tid & 63, wid = tid >> 6;  // wid 0..7
  const int wo = wid >> 1, wp = wid & 1;      // wave tile: o=wo*64, p=wp*32
  const int col = tid >> 3;  // producer column 0..63
  const int q = tid & 7;     // 8-ck chunk within step's 64-channel range

  const unsigned* xpb = xpair + (size_t)b * HW_ * 256;
  const int pg = h * W_ + col;

  // ---- hoist all 9 k's of meta into registers ----
  int2 miR[9];
  float4 mwR[9];
#pragma unroll
  for (int k = 0; k < 9; ++k) {
    miR[k] = midxg[(size_t)b * KK_ * HW_ + (size_t)k * HW_ + pg];
    mwR[k] = mwgtg[(size_t)b * KK_ * HW_ + (size_t)k * HW_ + pg];
  }

  f32x4 acc[4][2];
#pragma unroll
  for (int i = 0; i < 4; ++i)
#pragma unroll
    for (int j = 0; j < 2; ++j) acc[i][j] = (f32x4){0.f, 0.f, 0.f, 0.f};

  auto stageA = [&](int s, int buf) {
    const char* src = (const char*)(Wa + (size_t)s * 16384);
#pragma unroll
    for (int r = 0; r < 4; ++r) {
      const int chunk = r * 512 + tid;
      gload_lds16(src + chunk * 16, (char*)&Ald[buf][0] + chunk * 16);
    }
  };

  // gathers: thread covers ck = q*8..q*8+7 at its col; 2 rows x 2 uint4.
  auto issue = [&](int s, uint4& ga0, uint4& ga1, uint4& gb0, uint4& gb1) {
    const int k = s >> 2;
    const int c0 = (s & 3) * 64 + q * 8;
    const unsigned* r0 = xpb + (size_t)miR[k].x * 256 + c0;
    const unsigned* r1 = xpb + (size_t)miR[k].y * 256 + c0;
    ga0 = *(const uint4*)r0;
    ga1 = *(const uint4*)(r0 + 4);
    gb0 = *(const uint4*)r1;
    gb1 = *(const uint4*)(r1 + 4);
  };

  auto pack = [&](int s, const uint4 ga0, const uint4 ga1, const uint4 gb0,
                  const uint4 gb1, int4& pk) {
    const float4 mw = mwR[s >> 2];
    const unsigned a[8] = {ga0.x, ga0.y, ga0.z, ga0.w, ga1.x, ga1.y, ga1.z, ga1.w};
    const unsigned g[8] = {gb0.x, gb0.y, gb0.z, gb0.w, gb1.x, gb1.y, gb1.z, gb1.w};
    unsigned bf[8];
#pragma unroll
    for (int i = 0; i < 8; ++i) {
      float v = mw.x * bflo(a[i]) + mw.y * bfhi(a[i]) + mw.z * bflo(g[i]) +
                mw.w * bfhi(g[i]);
      bf[i] = f2bfu(v);
    }
    pk.x = bf[0] | (bf[1] << 16);
    pk.y = bf[2] | (bf[3] << 16);
    pk.z = bf[4] | (bf[5] << 16);
    pk.w = bf[6] | (bf[7] << 16);
  };

  // writer: ck = q*8+i -> kh = q>>2, kg = q&3, j = i; page = kh*4+kg = q.
  // Bank-swizzle col' = col ^ q. One 16B write per thread.
  const int bslot = (q >> 2) * 2048 + (q & 3) * 512 + (col ^ q) * 8;

  auto compute = [&](int buf) {
    const int kg = lane >> 4, rr = lane & 15;
    bf16x8 af[4][2], bfr[2][2];
#pragma unroll
    for (int kh = 0; kh < 2; ++kh) {
      const int page = kh * 4 + kg;
#pragma unroll
      for (int fm = 0; fm < 4; ++fm)
        af[fm][kh] = *(const bf16x8*)&Ald[buf][kh * 8192 + kg * 2048 +
                                              (wo * 64 + fm * 16 + rr) * 8];
#pragma unroll
      for (int fn = 0; fn < 2; ++fn) {
        const int rc = (wp * 32 + fn * 16 + rr) ^ page;
        bfr[fn][kh] = *(const bf16x8*)&Bld[buf][kh * 2048 + kg * 512 + rc * 8];
      }
    }
#pragma unroll
    for (int kh = 0; kh < 2; ++kh)
#pragma unroll
      for (int fm = 0; fm < 4; ++fm)
#pragma unroll
        for (int fn = 0; fn < 2; ++fn)
          acc[fm][fn] = __builtin_amdgcn_mfma_f32_16x16x32_bf16(
              af[fm][kh], bfr[fn][kh], acc[fm][fn], 0, 0, 0);
  };

  uint4 ga0, ga1, gb0, gb1;

  // ---- prologue: B(0) + A(0) into buf 0 ----
  {
    int4 pk;
    issue(0, ga0, ga1, gb0, gb1);
    pack(0, ga0, ga1, gb0, gb1, pk);
    *(int4*)&Bld[0][bslot] = pk;
    stageA(0, 0);
  }
  __syncthreads();

#pragma unroll
  for (int s = 0; s < 36; ++s) {
    const int cur = s & 1, nxt = cur ^ 1;
    if (s < 35) {
      issue(s + 1, ga0, ga1, gb0, gb1);  // gathers in flight during compute
      stageA(s + 1, nxt);
    }
    compute(cur);
    if (s < 35) {
      int4 pk;
      pack(s + 1, ga0, ga1, gb0, gb1, pk);
      *(int4*)&Bld[nxt][bslot] = pk;
    }
    __syncthreads();
  }

  // epilogue: BN + SiLU + store
  const float* bninv = bnbuf;
  const float* bnbb = bnbuf + 256;
  const int rr = lane & 15, rh = lane >> 4;
#pragma unroll
  for (int fm = 0; fm < 4; ++fm) {
#pragma unroll
    for (int r = 0; r < 4; ++r) {
      const int o = wo * 64 + fm * 16 + rh * 4 + r;
      const float inv = bninv[o], bb = bnbb[o];
#pragma unroll
      for (int fn = 0; fn < 2; ++fn) {
        float t = acc[fm][fn][r] * inv + bb;
        float sv = t / (1.f + expf(-t));
        out[(size_t)(b * C2_ + o) * HW_ + h * W_ + wp * 32 + fn * 16 + rr] = sv;
      }
    }
  }
}

// ---------------------------------------------------------------------------
extern "C" void kernel_launch(void* const* d_in, const int* in_sizes, int n_in,
                              void* d_out, int out_size, void* d_ws,
                              size_t ws_size, hipStream_t stream) {
  const float* x = (const float*)d_in[0];
  const float* w_om = (const float*)d_in[1];
  const float* b_om = (const float*)d_in[2];
  const float* w_dcn = (const float*)d_in[3];
  const float* bn_gamma = (const float*)d_in[4];
  const float* bn_beta = (const float*)d_in[5];
  const float* bn_mean = (const float*)d_in[6];
  const float* bn_var = (const float*)d_in[7];
  float* out = (float*)d_out;
  char* wsb = (char*)d_ws;

  unsigned short* Wa = (unsigned short*)(wsb + A_WA);
  unsigned short* xT = (unsigned short*)(wsb + A_XT);
  unsigned* xpair = (unsigned*)(wsb + A_XPAIR);
  int2* midx = (int2*)(wsb + A_MIDX);
  float4* mwgt = (float4*)(wsb + A_MWGT);
  unsigned short* Wom = (unsigned short*)(wsb + A_WOM);
  float* bnbuf = (float*)(wsb + A_BN);

  prep<<<1024 + 2304 + 288, 256, 0, stream>>>(x, w_om, w_dcn, bn_gamma,
                                              bn_beta, bn_mean, bn_var, xT,
                                              xpair, Wa, Wom, bnbuf);
  om_gemm<<<512, 256, 0, stream>>>(xT, b_om, Wom, midx, mwgt);
  dcn_fused<<<256, 512, 0, stream>>>(Wa, xpair, midx, mwgt, bnbuf, out);
}

// Round 22
// 72.889 us; speedup vs baseline: 1.1012x; 1.1012x over previous
//
#include <hip/hip_runtime.h>
#include <math.h>

#define B_  4
#define C1_ 256
#define C2_ 256
#define H_  64
#define W_  64
#define HW_ 4096
#define KK_ 9

// ws byte offsets (total ~30 MB; ws >= 97 MB proven in R9)
#define A_WA     0u           // bf16 Wa[72][4][256][8]       1,179,648
#define A_XT     1179648u     // bf16 xT[B][HW][C1]           8,388,608  (pos-major)
#define A_XPAIR  9568256u     // uint xpair[B][HW][C1]       16,777,216  (pos-major pairs)
#define A_MIDX   26345472u    // int2 midx[B][9][4096]        1,179,648
#define A_MWGT   27525120u    // float4 mwgt[B][9][4096]      2,359,296
#define A_WOM    29884416u    // bf16 Wom[72][4][32][8]         147,456
#define A_BN     30031872u    // float inv[256]; bb[256]          2,048

typedef short bf16x8 __attribute__((ext_vector_type(8)));
typedef float f32x4 __attribute__((ext_vector_type(4)));

__device__ __forceinline__ unsigned f2bfu(float f) {
  unsigned u = __builtin_bit_cast(unsigned, f);
  return (u + 0x7FFFu + ((u >> 16) & 1u)) >> 16;
}
__device__ __forceinline__ float bflo(unsigned g) {
  return __builtin_bit_cast(float, g << 16);
}
__device__ __forceinline__ float bfhi(unsigned g) {
  return __builtin_bit_cast(float, g & 0xFFFF0000u);
}
__device__ __forceinline__ void gload_lds16(const void* g, void* l) {
  __builtin_amdgcn_global_load_lds(
      (const __attribute__((address_space(1))) unsigned*)g,
      (__attribute__((address_space(3))) unsigned*)l, 16, 0, 0);
}

// grid 512: 8 XCDs; each XCD owns 32 consecutive rows of ONE batch.
__device__ __forceinline__ void decode_bid512(int bid, int& b, int& h, int& ph) {
  const int xcd = bid & 7, slot = bid >> 3;
  b = xcd >> 1;
  h = (xcd & 1) * 32 + (slot >> 1);
  ph = slot & 1;
}

// grid 256 variant: one full row h per block.
__device__ __forceinline__ void decode_bid256(int bid, int& b, int& h) {
  const int xcd = bid & 7, slot = bid >> 3;
  b = xcd >> 1;
  h = (xcd & 1) * 32 + slot;
}

// ---------------------------------------------------------------------------
// prep: transpose producing BOTH xT (bf16) and xpair (packed pos-pairs)
// (blocks 0..1023) + wt_perm (1024..3327) + wom_perm/BN (3328..3615).
// ---------------------------------------------------------------------------
__global__ __launch_bounds__(256) void prep(
    const float* __restrict__ x, const float* __restrict__ w_om,
    const float* __restrict__ w_dcn, const float* __restrict__ bn_gamma,
    const float* __restrict__ bn_beta, const float* __restrict__ bn_mean,
    const float* __restrict__ bn_var, unsigned short* __restrict__ xT,
    unsigned* __restrict__ xpair, unsigned short* __restrict__ Wa,
    unsigned short* __restrict__ Wom, float* __restrict__ bnbuf) {
  const int bid = blockIdx.x;
  const int tid = threadIdx.x;
  if (bid < 1024) {
    __shared__ unsigned short T[64][68];  // [c][pos-local 0..64], padded
    const int b = bid >> 8;
    const int rem = bid & 255;
    const int pos0 = (rem >> 2) * 64;
    const int c0 = (rem & 3) * 64;
    const int pl = tid & 63;
    const int ch = tid >> 6;
#pragma unroll
    for (int r = 0; r < 16; ++r) {
      const int cl = ch * 16 + r;
      const float v = x[((size_t)(b * C1_ + c0 + cl)) * HW_ + pos0 + pl];
      T[cl][pl] = (unsigned short)f2bfu(v);
    }
    if (tid < 64) {
      const int pe = min(pos0 + 64, HW_ - 1);
      T[tid][64] =
          (unsigned short)f2bfu(x[((size_t)(b * C1_ + c0 + tid)) * HW_ + pe]);
    }
    __syncthreads();
    unsigned short* dstT = xT + ((size_t)b * HW_ + pos0) * 256 + c0;
#pragma unroll
    for (int it = 0; it < 2; ++it) {
      const int q = it * 256 + tid;
      const int pp = q >> 3, cc = (q & 7) * 8;
      unsigned t0 = T[cc + 0][pp], t1 = T[cc + 1][pp], t2 = T[cc + 2][pp],
               t3 = T[cc + 3][pp], t4 = T[cc + 4][pp], t5 = T[cc + 5][pp],
               t6 = T[cc + 6][pp], t7 = T[cc + 7][pp];
      *(int4*)(dstT + (size_t)pp * 256 + cc) =
          make_int4(t0 | (t1 << 16), t2 | (t3 << 16), t4 | (t5 << 16),
                    t6 | (t7 << 16));
    }
    unsigned* dstP = xpair + ((size_t)b * HW_ + pos0) * 256 + c0;
#pragma unroll
    for (int it = 0; it < 4; ++it) {
      const int q = it * 256 + tid;
      const int pp = q >> 4;
      const int cc = (q & 15) * 4;
      unsigned p0 = (unsigned)T[cc + 0][pp] | ((unsigned)T[cc + 0][pp + 1] << 16);
      unsigned p1 = (unsigned)T[cc + 1][pp] | ((unsigned)T[cc + 1][pp + 1] << 16);
      unsigned p2 = (unsigned)T[cc + 2][pp] | ((unsigned)T[cc + 2][pp + 1] << 16);
      unsigned p3 = (unsigned)T[cc + 3][pp] | ((unsigned)T[cc + 3][pp + 1] << 16);
      *(uint4*)(dstP + (size_t)pp * 256 + cc) = make_uint4(p0, p1, p2, p3);
    }
  } else if (bid < 1024 + 2304) {
    const unsigned e = (bid - 1024) * 256 + tid;  // < 589824
    const unsigned kt = e >> 13, r2 = e & 8191;
    const unsigned kg = r2 >> 11, r3 = r2 & 2047, o = r3 >> 3, j = r3 & 7;
    const unsigned ck = kt * 32 + kg * 8 + j;
    const unsigned k = ck >> 8, c = ck & 255;
    Wa[e] = (unsigned short)f2bfu(w_dcn[((size_t)o * C1_ + c) * 9 + k]);
  } else {
    const int wb = bid - (1024 + 2304);
    if (wb == 0) {
      const int o = tid;
      float inv = bn_gamma[o] * rsqrtf(bn_var[o] + 1e-5f);
      bnbuf[o] = inv;
      bnbuf[256 + o] = bn_beta[o] - bn_mean[o] * inv;
    }
    const unsigned e = wb * 256 + tid;  // < 73728
    const unsigned kt = e >> 10, kg = (e >> 8) & 3, o = (e >> 3) & 31, j = e & 7;
    const unsigned ck = kt * 32 + kg * 8 + j;
    const unsigned k = ck >> 8, c = ck & 255;
    const float v = (o < 27) ? w_om[((size_t)o * C1_ + c) * 9 + k] : 0.f;
    Wom[e] = (unsigned short)f2bfu(v);
  }
}

// ---------------------------------------------------------------------------
// om_gemm: unchanged (xT producer). BK=128, 18 steps, grid 512.
// ---------------------------------------------------------------------------
__global__ __launch_bounds__(256) void om_gemm(
    const unsigned short* __restrict__ xT, const float* __restrict__ b_om,
    const unsigned short* __restrict__ Wom, int2* __restrict__ midx,
    float4* __restrict__ mwgt) {
  __shared__ short Ald[2][4096];
  __shared__ short Bld[2][4096];
  __shared__ float omld[32][33];

  int b, h, ph;
  decode_bid512(blockIdx.x, b, h, ph);
  const int tid = threadIdx.x;
  const int lane = tid & 63, wid = tid >> 6;
  const int wo = wid >> 1, wp = wid & 1;
  const int p = tid & 31;
  const int cr = tid >> 5;

  const unsigned short* xTb = xT + (size_t)b * HW_ * 256;

  f32x4 acc = (f32x4){0.f, 0.f, 0.f, 0.f};

  auto stageA = [&](int s, int buf) {
    const char* src = (const char*)(Wom + (size_t)s * 4096);
    gload_lds16(src + tid * 16, (char*)&Ald[buf][0] + tid * 16);
    gload_lds16(src + (256 + tid) * 16, (char*)&Ald[buf][0] + (256 + tid) * 16);
  };

  auto produce = [&](int s, int4& uA, int4& uB) {
    const int k = s >> 1;
    const int c0 = (s & 1) * 128 + cr * 16;
    const int hh = h - 1 + k / 3;
    const int ww = ph * 32 + p - 1 + k % 3;
    const bool v = ((unsigned)hh < (unsigned)H_) && ((unsigned)ww < (unsigned)W_);
    const unsigned short* pl = xTb + (size_t)(v ? hh * W_ + ww : 0) * 256 + c0;
    uA = v ? *(const int4*)pl : make_int4(0, 0, 0, 0);
    uB = v ? *(const int4*)(pl + 8) : make_int4(0, 0, 0, 0);
  };

  const int bslot = (cr * 2) * 256 + p * 8;

  auto compute = [&](int buf) {
    const int kg = lane >> 4, rr = lane & 15;
#pragma unroll
    for (int kh = 0; kh < 4; ++kh) {
      bf16x8 af = *(const bf16x8*)&Ald[buf][(kh * 4 + kg) * 256 + (wo * 16 + rr) * 8];
      bf16x8 bfr = *(const bf16x8*)&Bld[buf][(kh * 4 + kg) * 256 + (wp * 16 + rr) * 8];
      acc = __builtin_amdgcn_mfma_f32_16x16x32_bf16(af, bfr, acc, 0, 0, 0);
    }
  };

  {
    int4 uA, uB;
    produce(0, uA, uB);
    *(int4*)&Bld[0][bslot] = uA;
    *(int4*)&Bld[0][bslot + 256] = uB;
    stageA(0, 0);
  }
  __syncthreads();

  for (int s = 0; s < 18; ++s) {
    const int cur = s & 1, nxt = cur ^ 1;
    const bool pre = (s < 17);
    int4 uA, uB;
    if (pre) {
      produce(s + 1, uA, uB);
      stageA(s + 1, nxt);
    }
    compute(cur);
    if (pre) {
      *(int4*)&Bld[nxt][bslot] = uA;
      *(int4*)&Bld[nxt][bslot + 256] = uB;
    }
    __syncthreads();
  }

  {
    const int rr = lane & 15, rh = lane >> 4;
#pragma unroll
    for (int r = 0; r < 4; ++r) omld[wo * 16 + rh * 4 + r][wp * 16 + rr] = acc[r];
  }
  __syncthreads();

  if (tid < 32) {
    const int pc = tid;
    float a[27];
#pragma unroll
    for (int oc = 0; oc < 27; ++oc) a[oc] = omld[oc][pc] + b_om[oc];

    const int pcol = ph * 32 + pc;
#pragma unroll
    for (int k = 0; k < 9; ++k) {
      float dy = fminf(fmaxf(a[2 * k], -6.f), 6.f);
      float dx = fminf(fmaxf(a[2 * k + 1], -6.f), 6.f);
      float m = 1.f / (1.f + expf(-a[18 + k]));
      float py = (float)(h - 1 + k / 3) + dy;
      float px = (float)(pcol - 1 + k % 3) + dx;
      float y0f = floorf(py), x0f = floorf(px);
      float ly = py - y0f, lx = px - x0f;
      int y0 = (int)y0f, x0 = (int)x0f;
      int y1 = y0 + 1, x1 = x0 + 1;
      const bool vy0 = ((unsigned)y0 < (unsigned)H_);
      const bool vy1 = ((unsigned)y1 < (unsigned)H_);
      const bool vx0 = ((unsigned)x0 < (unsigned)W_);
      const bool vx1 = ((unsigned)x1 < (unsigned)W_);
      int y0c = min(max(y0, 0), H_ - 1), y1c = min(max(y1, 0), H_ - 1);
      int x0c = min(max(x0, 0), W_ - 1), x1c = min(max(x1, 0), W_ - 1);
      const int xbc = min(max(x0, 0), W_ - 2);
      float wx0 = 0.f, wx1 = 0.f;
      if (vx0) { if (x0c == xbc) wx0 += 1.f - lx; else wx1 += 1.f - lx; }
      if (vx1) { if (x1c == xbc) wx0 += lx; else wx1 += lx; }
      const float wy0 = vy0 ? (1.f - ly) : 0.f;
      const float wy1 = vy1 ? ly : 0.f;
      const size_t e = ((size_t)b * KK_ + k) * HW_ + h * W_ + pcol;
      midx[e] = make_int2(y0c * W_ + xbc, y1c * W_ + xbc);
      mwgt[e] = make_float4(m * wy0 * wx0, m * wy0 * wx1, m * wy1 * wx0,
                            m * wy1 * wx1);
    }
  }
}

// ---------------------------------------------------------------------------
// dcn_fused: R19 config (best: 47.0 us) + s_setprio around MFMA cluster.
// O=256 x P=64, 1024 thr = 16 waves (wave 32o x 32p), grid 256, swizzled B,
// 2-deep gather pipeline with counted vmcnt(2).
// ---------------------------------------------------------------------------
__global__ __launch_bounds__(1024, 4) void dcn_fused(
    const unsigned short* __restrict__ Wa, const unsigned* __restrict__ xpair,
    const int2* __restrict__ midxg, const float4* __restrict__ mwgtg,
    const float* __restrict__ bnbuf, float* __restrict__ out) {
  __shared__ short Ald[2][16384];  // [2 kh][4 kg][256 o][8 j]  32 KB/buf
  __shared__ short Bld[2][4096];   // [2 kh][4 kg][64 col'][8 j] 8 KB/buf

  int b, h;
  decode_bid256(blockIdx.x, b, h);
  const int tid = threadIdx.x;
  const int lane = tid & 63, wid = tid >> 6;  // wid 0..15
  const int wo = wid >> 1, wp = wid & 1;      // wave tile: o=wo*32, p=wp*32
  const int col = tid >> 4;  // producer column 0..63
  const int q = tid & 15;    // 16B chunk within step's 64-channel range

  const unsigned* xpb = xpair + (size_t)b * HW_ * 256;
  const int pg = h * W_ + col;

  // ---- hoist all 9 k's of meta into registers ----
  int2 miR[9];
  float4 mwR[9];
#pragma unroll
  for (int k = 0; k < 9; ++k) {
    miR[k] = midxg[(size_t)b * KK_ * HW_ + (size_t)k * HW_ + pg];
    mwR[k] = mwgtg[(size_t)b * KK_ * HW_ + (size_t)k * HW_ + pg];
  }

  f32x4 acc[2][2];
#pragma unroll
  for (int i = 0; i < 2; ++i)
#pragma unroll
    for (int j = 0; j < 2; ++j) acc[i][j] = (f32x4){0.f, 0.f, 0.f, 0.f};

  auto stageA = [&](int s, int buf) {
    const char* src = (const char*)(Wa + (size_t)s * 16384);
#pragma unroll
    for (int r = 0; r < 2; ++r) {
      const int chunk = r * 1024 + tid;
      gload_lds16(src + chunk * 16, (char*)&Ald[buf][0] + chunk * 16);
    }
  };

  // coalesced gathers: 16 lanes read 16 consecutive 16B chunks of one row
  auto issue = [&](int s, uint4& ga, uint4& gb) {
    const int k = s >> 2;
    const int c0 = (s & 3) * 64 + q * 4;
    ga = *(const uint4*)(xpb + (size_t)miR[k].x * 256 + c0);
    gb = *(const uint4*)(xpb + (size_t)miR[k].y * 256 + c0);
  };

  auto pack = [&](int s, const uint4 ga, const uint4 gb, int2& pk) {
    const float4 mw = mwR[s >> 2];
    const unsigned a[4] = {ga.x, ga.y, ga.z, ga.w};
    const unsigned g[4] = {gb.x, gb.y, gb.z, gb.w};
    unsigned bf[4];
#pragma unroll
    for (int i = 0; i < 4; ++i) {
      float v = mw.x * bflo(a[i]) + mw.y * bfhi(a[i]) + mw.z * bflo(g[i]) +
                mw.w * bfhi(g[i]);
      bf[i] = f2bfu(v);
    }
    pk.x = bf[0] | (bf[1] << 16);
    pk.y = bf[2] | (bf[3] << 16);
  };

  // writer: kk = q*4+i -> kh = q>>3, kg = (q>>1)&3, j0 = (q&1)*4;
  // page = q>>1; bank-swizzle col' = col ^ page.
  const int bslot =
      (q >> 3) * 2048 + ((q >> 1) & 3) * 512 + (col ^ (q >> 1)) * 8 + (q & 1) * 4;

  auto compute = [&](int buf) {
    const int kg = lane >> 4, rr = lane & 15;
    bf16x8 af[2][2], bfr[2][2];
#pragma unroll
    for (int kh = 0; kh < 2; ++kh) {
      const int page = kh * 4 + kg;
#pragma unroll
      for (int fm = 0; fm < 2; ++fm)
        af[fm][kh] = *(const bf16x8*)&Ald[buf][kh * 8192 + kg * 2048 +
                                              (wo * 32 + fm * 16 + rr) * 8];
#pragma unroll
      for (int fn = 0; fn < 2; ++fn) {
        const int rc = (wp * 32 + fn * 16 + rr) ^ page;
        bfr[fn][kh] = *(const bf16x8*)&Bld[buf][kh * 2048 + kg * 512 + rc * 8];
      }
    }
    __builtin_amdgcn_s_setprio(1);
#pragma unroll
    for (int kh = 0; kh < 2; ++kh)
#pragma unroll
      for (int fm = 0; fm < 2; ++fm)
#pragma unroll
        for (int fn = 0; fn < 2; ++fn)
          acc[fm][fn] = __builtin_amdgcn_mfma_f32_16x16x32_bf16(
              af[fm][kh], bfr[fn][kh], acc[fm][fn], 0, 0, 0);
    __builtin_amdgcn_s_setprio(0);
  };

  uint4 ga_e, gb_e, ga_o, gb_o;

  // ---- prologue ----
  // issue G(0); pack B0 (auto-wait G0); stageA(0); issue G(1);
  // vmcnt(2): A(0) complete, G(1) in flight across the barrier.
  issue(0, ga_e, gb_e);
  {
    int2 pk;
    pack(0, ga_e, gb_e, pk);
    *(int2*)&Bld[0][bslot] = pk;
  }
  stageA(0, 0);
  issue(1, ga_o, gb_o);
  asm volatile("s_waitcnt vmcnt(2) lgkmcnt(0)" ::: "memory");
  __builtin_amdgcn_s_barrier();
  __builtin_amdgcn_sched_barrier(0);

#define STEP(S, GAP, GBP, GAN, GBN)                                  \
  {                                                                  \
    if ((S) + 1 < 36) {                                              \
      int2 pk;                                                       \
      pack((S) + 1, GAP, GBP, pk);                                   \
      *(int2*)&Bld[((S) + 1) & 1][bslot] = pk;                       \
      stageA((S) + 1, ((S) + 1) & 1);                                \
    }                                                                \
    if ((S) + 2 < 36) issue((S) + 2, GAN, GBN);                      \
    compute((S) & 1);                                                \
    if ((S) + 1 < 36) {                                              \
      if ((S) + 2 < 36) {                                            \
        asm volatile("s_waitcnt vmcnt(2) lgkmcnt(0)" ::: "memory");  \
      } else {                                                       \
        asm volatile("s_waitcnt vmcnt(0) lgkmcnt(0)" ::: "memory");  \
      }                                                              \
      __builtin_amdgcn_s_barrier();                                  \
      __builtin_amdgcn_sched_barrier(0);                             \
    }                                                                \
  }

#pragma unroll
  for (int sb = 0; sb < 36; sb += 2) {
    STEP(sb, ga_o, gb_o, ga_e, gb_e);      // even s: pack G(s+1), issue G(s+2)
    STEP(sb + 1, ga_e, gb_e, ga_o, gb_o);  // odd s
  }
#undef STEP

  // epilogue: BN + SiLU + store
  const float* bninv = bnbuf;
  const float* bnbb = bnbuf + 256;
  const int rr = lane & 15, rh = lane >> 4;
#pragma unroll
  for (int fm = 0; fm < 2; ++fm) {
#pragma unroll
    for (int r = 0; r < 4; ++r) {
      const int o = wo * 32 + fm * 16 + rh * 4 + r;
      const float inv = bninv[o], bb = bnbb[o];
#pragma unroll
      for (int fn = 0; fn < 2; ++fn) {
        float t = acc[fm][fn][r] * inv + bb;
        float sv = t / (1.f + expf(-t));
        out[(size_t)(b * C2_ + o) * HW_ + h * W_ + wp * 32 + fn * 16 + rr] = sv;
      }
    }
  }
}

// ---------------------------------------------------------------------------
extern "C" void kernel_launch(void* const* d_in, const int* in_sizes, int n_in,
                              void* d_out, int out_size, void* d_ws,
                              size_t ws_size, hipStream_t stream) {
  const float* x = (const float*)d_in[0];
  const float* w_om = (const float*)d_in[1];
  const float* b_om = (const float*)d_in[2];
  const float* w_dcn = (const float*)d_in[3];
  const float* bn_gamma = (const float*)d_in[4];
  const float* bn_beta = (const float*)d_in[5];
  const float* bn_mean = (const float*)d_in[6];
  const float* bn_var = (const float*)d_in[7];
  float* out = (float*)d_out;
  char* wsb = (char*)d_ws;

  unsigned short* Wa = (unsigned short*)(wsb + A_WA);
  unsigned short* xT = (unsigned short*)(wsb + A_XT);
  unsigned* xpair = (unsigned*)(wsb + A_XPAIR);
  int2* midx = (int2*)(wsb + A_MIDX);
  float4* mwgt = (float4*)(wsb + A_MWGT);
  unsigned short* Wom = (unsigned short*)(wsb + A_WOM);
  float* bnbuf = (float*)(wsb + A_BN);

  prep<<<1024 + 2304 + 288, 256, 0, stream>>>(x, w_om, w_dcn, bn_gamma,
                                              bn_beta, bn_mean, bn_var, xT,
                                              xpair, Wa, Wom, bnbuf);
  om_gemm<<<512, 256, 0, stream>>>(xT, b_om, Wom, midx, mwgt);
  dcn_fused<<<256, 1024, 0, stream>>>(Wa, xpair, midx, mwgt, bnbuf, out);
}